// Round 6
// baseline (522.156 us; speedup 1.0000x reference)
//
#include <hip/hip_runtime.h>
#include <hip/hip_fp16.h>
#include <math.h>

// Problem constants
#define V    20000
#define SCV  4000
#define LL   15
#define OUTN (16384 * 128)   // B*S*D

#define LEAF_BIT 0x40000000
#define REF_MASK 0x3FFFFFFF
#define ROOT_BIT 0x20000000   // on E.x only: node is a tree root (write hInt only)
#define SLOT_MASK 0x1FFFFFFF
#define DUMMY_SLOT 89999     // total internal nodes ~80k < 89999

// ---- workspace layout (bytes) ----
#define OFF_COUNTS 0
#define OFF_ROOT   128
#define OFF_LISTS  80384
#define OFF_LEAFC  5968384
#define OFF_LEAFHH 8016384
#define OFF_WT     19280384
#define OFF_BIAS   19608064
#define OFF_HINT   19610624
#define OFF_CINT   65690624
#define OFF_HH     111770624
#define OFF_USED   134810624

// per-height lists: h1@0 (cap 80000), h2@80000, h3@120000, h4@160000,
// h5@180000, h6@200000, h7@220000
__device__ __constant__ int d_listOff[8] = {0, 0, 80000, 120000, 160000, 180000, 200000, 220000};

#define MT 128

typedef _Float16 f16x8 __attribute__((ext_vector_type(8)));
typedef float    f32x4 __attribute__((ext_vector_type(4)));

__device__ __forceinline__ float sigm(float x) { return 1.0f / (1.0f + expf(-x)); }

// ---------------- prep: leaf states + WT transpose + biasSum + mark ----------------
// grid 1024 x 256. Blocks 0..39 also do one 64x64 WT tile; block 41 does biasSum.
__global__ void prep_kernel(const int* __restrict__ input,
                            const float* __restrict__ emb,
                            const float* __restrict__ Wl, const float* __restrict__ Wlb,
                            const float* __restrict__ Wr, const float* __restrict__ Wrb,
                            float* __restrict__ leafC, __half* __restrict__ leafHh,
                            __half* __restrict__ WT, float* __restrict__ biasSum,
                            unsigned char* __restrict__ used) {
    __shared__ float T[64][65];
    int t = threadIdx.x, bid = blockIdx.x;
    // leaf (h,c) per sub-char id: 2 rows per block-iter
    for (int r = bid * 2 + (t >> 7); r < SCV; r += gridDim.x * 2) {
        int i = t & 127;
        const float* e = emb + r * 640;
        float c = sigm(e[i]) * tanhf(e[512 + i]);
        float h = sigm(e[384 + i]) * tanhf(c);
        leafC[r * 128 + i] = c;
        leafHh[r * 128 + i] = __float2half(h);
    }
    // mark used tokens
    for (int i = bid * 256 + t; i < 16384; i += gridDim.x * 256)
        used[input[i]] = 1;
    // bias sum
    if (bid == 41)
        for (int i = t; i < 640; i += 256) biasSum[i] = Wlb[i] + Wrb[i];
    // WT[n][k] = fp16([Wl;Wr][k][n]); 40 tiles of 64x64, one per block 0..39
    if (bid < 40) {
        int kb = (bid & 3) * 64, nb = (bid >> 2) * 64;
        int tx = t & 63, ty = t >> 6;            // 256 threads: ty 0..3
        for (int kk = ty; kk < 64; kk += 4) {
            int k = kb + kk;
            const float* Wsrc = (k < 128) ? (Wl + k * 640) : (Wr + (k - 128) * 640);
            T[kk][tx] = Wsrc[nb + tx];
        }
        __syncthreads();
        for (int nn = ty; nn < 64; nn += 4)
            WT[(nb + nn) * 256 + kb + tx] = __float2half(T[tx][nn]);
    }
}

// ---------------- metadata: heights, compact slots, per-height lists ----------------
__global__ void meta_kernel(const int* __restrict__ node_ids,
                            const int* __restrict__ left,
                            const int* __restrict__ right,
                            const int* __restrict__ last,
                            const unsigned char* __restrict__ used,
                            int* __restrict__ counts,
                            int* __restrict__ rootSlot,
                            int4* __restrict__ lists) {
    __shared__ int  sHei[MT][17];
    __shared__ int  sRef[MT][17];
    __shared__ int4 ebuf[MT][7];
    __shared__ int  ebin[MT][7];
    __shared__ int  locCnt[8];
    __shared__ int  basePos[8];
    __shared__ int  scanBuf[MT];
    __shared__ int  blockBase;

    int tid = threadIdx.x;
    if (tid < 8) locCnt[tid] = 0;
    __syncthreads();

    int v = blockIdx.x * MT + tid;
    int nInt = 0;
    if (v < V && used[v]) {
        int l15[LL], r15[LL], id15[LL];
#pragma unroll
        for (int j = 0; j < LL; ++j) {
            l15[j]  = left[v * LL + j];
            r15[j]  = right[v * LL + j];
            id15[j] = node_ids[v * LL + j];
        }
        int lastv = last[v];
#pragma unroll
        for (int j = 0; j < LL; ++j) {
            if (j <= lastv) {
                int l = l15[j];
                if (l < 0) {
                    sHei[tid][j] = 0;
                    sRef[tid][j] = LEAF_BIT | id15[j];
                } else {
                    int r = r15[j];
                    int hl = sHei[tid][l], hr = sHei[tid][r];
                    int hh = 1 + (hl > hr ? hl : hr);
                    sHei[tid][j] = hh;
                    int pos = atomicAdd(&locCnt[hh], 1);
                    int flag = (j == lastv) ? ROOT_BIT : 0;
                    ebuf[tid][nInt] = make_int4(nInt | flag, id15[j], sRef[tid][l], sRef[tid][r]);
                    ebin[tid][nInt] = (hh << 16) | pos;
                    sRef[tid][j] = nInt;
                    ++nInt;
                }
            }
        }
    }
    // block-level inclusive scan of nInt -> compact slot bases
    scanBuf[tid] = nInt;
    __syncthreads();
    for (int d = 1; d < MT; d <<= 1) {
        int val = (tid >= d) ? scanBuf[tid - d] : 0;
        __syncthreads();
        scanBuf[tid] += val;
        __syncthreads();
    }
    if (tid == 0) blockBase = atomicAdd(&counts[31], scanBuf[MT - 1]);
    if (tid < 8) {
        int c = locCnt[tid];
        basePos[tid] = c ? atomicAdd(&counts[tid], c) : 0;
    }
    __syncthreads();
    int treeBase = blockBase + scanBuf[tid] - nInt;
    if (v < V && nInt > 0) rootSlot[v] = treeBase + nInt - 1;
    for (int e = 0; e < nInt; ++e) {
        int4 E  = ebuf[tid][e];
        int md  = ebin[tid][e];
        int hh  = md >> 16, pos = md & 0xFFFF;
        E.x += treeBase;                                   // ROOT_BIT preserved
        E.z = (E.z & LEAF_BIT) ? E.z : (E.z + treeBase);
        E.w = (E.w & LEAF_BIT) ? E.w : (E.w + treeBase);
        lists[d_listOff[hh] + basePos[hh] + pos] = E;
    }
}

// ---------------- MFMA round: all heights 1..7, unified K=256 ----------------
// Sync-free version: NO LDS, NO __syncthreads. Each lane loads its A fragment
// slice (16B of a child h-row) directly from global; the 8 waves' re-reads of
// the same 32 child rows hit L1 (16KB working set). Meta read per-lane from
// list[] (L1/L2-hot, quad-broadcast addresses). Every wave free-runs its own
// load/MFMA pipeline -> no barrier convoy, no LDS round-trip, 0 bank conflicts.
// Mapping unchanged: 32 nodes/group, wave w owns cols {128p + 16w + ln15}.
__launch_bounds__(512, 4)
__global__ void round_mfma(const int4* __restrict__ list, const int* __restrict__ cntPtr,
                           const float* __restrict__ emb, const __half* __restrict__ WT,
                           const float* __restrict__ biasSum,
                           const __half* __restrict__ leafHh, const float* __restrict__ leafC,
                           float* __restrict__ hInt, float* __restrict__ cInt,
                           __half* __restrict__ hH) {
    int cnt = *cntPtr;
    int nGroups = (cnt + 31) >> 5;
    int t = threadIdx.x;
    int lane = t & 63, wave = t >> 6;        // 8 waves
    int ln15 = lane & 15, quad = lane >> 4;
    float bs[5];
#pragma unroll
    for (int p = 0; p < 5; ++p) bs[p] = biasSum[p * 128 + 16 * wave + ln15];
    const __half* wbase = WT + (16 * wave + ln15) * 256 + quad * 8;
    int d = 16 * wave + ln15;

    for (int grp = blockIdx.x; grp < nGroups; grp += gridDim.x) {
        int base = grp * 32;
        // ---- A-row refs for this lane (rows c*16+ln15): left/right child ptrs ----
        const __half* aP[2][2];
#pragma unroll
        for (int c = 0; c < 2; ++c) {
            int m = c * 16 + ln15;
            int rz = LEAF_BIT, rw = LEAF_BIT;
            if (base + m < cnt) { int4 E = list[base + m]; rz = E.z; rw = E.w; }
            aP[c][0] = ((rz & LEAF_BIT) ? leafHh : hH) + (rz & REF_MASK) * 128;
            aP[c][1] = ((rw & LEAF_BIT) ? leafHh : hH) + (rw & REF_MASK) * 128;
        }
        // ---- C init: emb + (Wlb+Wrb); gate p at col offset 128p ----
        f32x4 acc[2][5];
#pragma unroll
        for (int c = 0; c < 2; ++c)
#pragma unroll
            for (int r = 0; r < 4; ++r) {
                int m = c * 16 + quad * 4 + r;
                int id = (base + m < cnt) ? list[base + m].y : 0;
                const float* eb = emb + id * 640 + d;
#pragma unroll
                for (int p = 0; p < 5; ++p)
                    acc[c][p][r] = eb[p * 128] + bs[p];
            }
        // ---- K loop: fully unrolled (static aP[c][side] indices, no scratch) ----
#pragma unroll
        for (int kb = 0; kb < 8; ++kb) {
            const int side = kb >> 2;            // 0: left child (k 0..127), 1: right
            const int ko   = (kb & 3) * 32 + quad * 8;
            f16x8 af[2];
#pragma unroll
            for (int c = 0; c < 2; ++c)
                af[c] = *(const f16x8*)((const void*)(aP[c][side] + ko));
            f16x8 bf[5];
#pragma unroll
            for (int p = 0; p < 5; ++p)
                bf[p] = *(const f16x8*)((const void*)(wbase + p * 32768 + kb * 32));
#pragma unroll
            for (int p = 0; p < 5; ++p)
#pragma unroll
                for (int c = 0; c < 2; ++c)
                    acc[c][p] = __builtin_amdgcn_mfma_f32_16x16x32_f16(af[c], bf[p], acc[c][p], 0, 0, 0);
        }
        // ---- in-register LSTM epilogue: dim d, gates = p; meta reloaded (L1-hot) ----
#pragma unroll
        for (int c = 0; c < 2; ++c)
#pragma unroll
            for (int r = 0; r < 4; ++r) {
                int m = c * 16 + quad * 4 + r;
                int4 E;
                if (base + m < cnt) E = list[base + m];
                else { E.x = DUMMY_SLOT; E.y = 0; E.z = LEAF_BIT; E.w = LEAF_BIT; }
                float ig = acc[c][0][r], lfg = acc[c][1][r], rfg = acc[c][2][r];
                float og = acc[c][3][r], ug = acc[c][4][r];
                float cl = ((E.z & LEAF_BIT) ? leafC : cInt)[(E.z & REF_MASK) * 128 + d];
                float cr = ((E.w & LEAF_BIT) ? leafC : cInt)[(E.w & REF_MASK) * 128 + d];
                float cc = sigm(ig) * tanhf(ug) + sigm(lfg) * cl + sigm(rfg) * cr;
                float hh2 = sigm(og) * tanhf(cc);
                int slot = E.x & SLOT_MASK;
                if (E.x & ROOT_BIT) {
                    hInt[slot * 128 + d] = hh2;      // root: only f32 h is read (gather)
                } else {
                    cInt[slot * 128 + d] = cc;       // non-root: c + fp16 h are read
                    hH[slot * 128 + d] = __float2half(hh2);
                }
            }
    }
}

// ---------------- final gather: out[b,s,:] = h_root[input[b,s]] ----------------
__global__ void gather_kernel(const int* __restrict__ input,
                              const int* __restrict__ rootSlot,
                              const float* __restrict__ hInt,
                              float4* __restrict__ out) {
    int idx = blockIdx.x * 256 + threadIdx.x;   // < OUTN/4
    int token = input[idx >> 5];
    int d = idx & 31;
    out[idx] = ((const float4*)hInt)[rootSlot[token] * 32 + d];
}

extern "C" void kernel_launch(void* const* d_in, const int* in_sizes, int n_in,
                              void* d_out, int out_size, void* d_ws, size_t ws_size,
                              hipStream_t stream) {
    const int*   input    = (const int*)d_in[0];
    const int*   node_ids = (const int*)d_in[1];
    const int*   left     = (const int*)d_in[2];
    const int*   right    = (const int*)d_in[3];
    const int*   last     = (const int*)d_in[4];
    const float* emb      = (const float*)d_in[5];
    const float* Wl       = (const float*)d_in[6];
    const float* Wlb      = (const float*)d_in[7];
    const float* Wr       = (const float*)d_in[8];
    const float* Wrb      = (const float*)d_in[9];
    float* out = (float*)d_out;

    char* ws = (char*)d_ws;
    int*    counts   = (int*)(ws + OFF_COUNTS);
    int*    rootSlot = (int*)(ws + OFF_ROOT);
    int4*   lists    = (int4*)(ws + OFF_LISTS);
    float*  leafC    = (float*)(ws + OFF_LEAFC);
    __half* leafHh   = (__half*)(ws + OFF_LEAFHH);
    __half* WT       = (__half*)(ws + OFF_WT);
    float*  biasSum  = (float*)(ws + OFF_BIAS);
    float*  hInt     = (float*)(ws + OFF_HINT);
    float*  cInt     = (float*)(ws + OFF_CINT);
    __half* hH       = (__half*)(ws + OFF_HH);
    unsigned char* usedp = (unsigned char*)(ws + OFF_USED);

    (void)hipMemsetAsync(counts, 0, 128, stream);
    (void)hipMemsetAsync(usedp, 0, V, stream);

    prep_kernel<<<1024, 256, 0, stream>>>(input, emb, Wl, Wlb, Wr, Wrb,
                                          leafC, leafHh, WT, biasSum, usedp);
    meta_kernel<<<(V + MT - 1) / MT, MT, 0, stream>>>(node_ids, left, right, last, usedp,
                                                      counts, rootSlot, lists);

    static const int h_listOff[8] = {0, 0, 80000, 120000, 160000, 180000, 200000, 220000};
    static const int h_grid[8]    = {0, 1024, 512, 256, 128, 32, 16, 8};
    for (int h = 1; h <= 7; ++h) {
        round_mfma<<<h_grid[h], 512, 0, stream>>>(
            lists + h_listOff[h], counts + h,
            emb, WT, biasSum, leafHh, leafC, hInt, cInt, hH);
    }

    gather_kernel<<<OUTN / 4 / 256, 256, 0, stream>>>(input, rootSlot, hInt, (float4*)out);
}

// Round 7
// 467.644 us; speedup vs baseline: 1.1166x; 1.1166x over previous
//
#include <hip/hip_runtime.h>
#include <hip/hip_fp16.h>
#include <math.h>

// Problem constants
#define V    20000
#define SCV  4000
#define LL   15
#define OUTN (16384 * 128)   // B*S*D

#define LEAF_BIT 0x40000000
#define REF_MASK 0x3FFFFFFF
#define ROOT_BIT 0x20000000   // on E.x only: node is a tree root (write hInt only)
#define SLOT_MASK 0x1FFFFFFF
#define DUMMY_SLOT 89999     // total internal nodes ~80k < 89999

// ---- workspace layout (bytes) ----
#define OFF_COUNTS 0
#define OFF_ROOT   128
#define OFF_LISTS  80384
#define OFF_LEAFC  5968384
#define OFF_LEAFHH 8016384
#define OFF_EMBT   9040384     // fp16 [4000][128][8] = 8.192 MB (old LT/RT slot)
#define OFF_WT     19280384
#define OFF_BIAS   19608064
#define OFF_HINT   19610624
#define OFF_CINT   65690624
#define OFF_HH     111770624
#define OFF_USED   134810624

// per-height lists: h1@0 (cap 80000), h2@80000, h3@120000, h4@160000,
// h5@180000, h6@200000, h7@220000
__device__ __constant__ int d_listOff[8] = {0, 0, 80000, 120000, 160000, 180000, 200000, 220000};

#define MT 128

typedef _Float16 f16x8 __attribute__((ext_vector_type(8)));
typedef float    f32x4 __attribute__((ext_vector_type(4)));

__device__ __forceinline__ float sigm(float x) { return 1.0f / (1.0f + expf(-x)); }

// ---------------- prep: leaf states + embT + WT transpose + biasSum + mark ----------
// grid 1024 x 256. Blocks 0..39 also do one 64x64 WT tile; block 41 does biasSum.
__global__ void prep_kernel(const int* __restrict__ input,
                            const float* __restrict__ emb,
                            const float* __restrict__ Wl, const float* __restrict__ Wlb,
                            const float* __restrict__ Wr, const float* __restrict__ Wrb,
                            float* __restrict__ leafC, __half* __restrict__ leafHh,
                            __half* __restrict__ embT,
                            __half* __restrict__ WT, float* __restrict__ biasSum,
                            unsigned char* __restrict__ used) {
    __shared__ float T[64][65];
    int t = threadIdx.x, bid = blockIdx.x;
    // leaf (h,c) per sub-char id: 2 rows per block-iter
    for (int r = bid * 2 + (t >> 7); r < SCV; r += gridDim.x * 2) {
        int i = t & 127;
        const float* e = emb + r * 640;
        float c = sigm(e[i]) * tanhf(e[512 + i]);
        float h = sigm(e[384 + i]) * tanhf(c);
        leafC[r * 128 + i] = c;
        leafHh[r * 128 + i] = __float2half(h);
    }
    // embT[id][d][0..4] = fp16(emb[id][p*128+d]), [5..7]=0  (one 16B row per (id,d))
    for (int idx = bid * 256 + t; idx < SCV * 128; idx += gridDim.x * 256) {
        int id = idx >> 7, dd = idx & 127;
        const float* e = emb + id * 640 + dd;
        __half v[8];
#pragma unroll
        for (int p = 0; p < 5; ++p) v[p] = __float2half(e[p * 128]);
        v[5] = __float2half(0.f); v[6] = v[5]; v[7] = v[5];
        *(uint4*)(embT + (size_t)idx * 8) = *(const uint4*)v;
    }
    // mark used tokens
    for (int i = bid * 256 + t; i < 16384; i += gridDim.x * 256)
        used[input[i]] = 1;
    // bias sum
    if (bid == 41)
        for (int i = t; i < 640; i += 256) biasSum[i] = Wlb[i] + Wrb[i];
    // WT[n][k] = fp16([Wl;Wr][k][n]); 40 tiles of 64x64, one per block 0..39
    if (bid < 40) {
        int kb = (bid & 3) * 64, nb = (bid >> 2) * 64;
        int tx = t & 63, ty = t >> 6;            // 256 threads: ty 0..3
        for (int kk = ty; kk < 64; kk += 4) {
            int k = kb + kk;
            const float* Wsrc = (k < 128) ? (Wl + k * 640) : (Wr + (k - 128) * 640);
            T[kk][tx] = Wsrc[nb + tx];
        }
        __syncthreads();
        for (int nn = ty; nn < 64; nn += 4)
            WT[(nb + nn) * 256 + kb + tx] = __float2half(T[tx][nn]);
    }
}

// ---------------- metadata: heights, compact slots, per-height lists ----------------
__global__ void meta_kernel(const int* __restrict__ node_ids,
                            const int* __restrict__ left,
                            const int* __restrict__ right,
                            const int* __restrict__ last,
                            const unsigned char* __restrict__ used,
                            int* __restrict__ counts,
                            int* __restrict__ rootSlot,
                            int4* __restrict__ lists) {
    __shared__ int  sHei[MT][17];
    __shared__ int  sRef[MT][17];
    __shared__ int4 ebuf[MT][7];
    __shared__ int  ebin[MT][7];
    __shared__ int  locCnt[8];
    __shared__ int  basePos[8];
    __shared__ int  scanBuf[MT];
    __shared__ int  blockBase;

    int tid = threadIdx.x;
    if (tid < 8) locCnt[tid] = 0;
    __syncthreads();

    int v = blockIdx.x * MT + tid;
    int nInt = 0;
    if (v < V && used[v]) {
        int l15[LL], r15[LL], id15[LL];
#pragma unroll
        for (int j = 0; j < LL; ++j) {
            l15[j]  = left[v * LL + j];
            r15[j]  = right[v * LL + j];
            id15[j] = node_ids[v * LL + j];
        }
        int lastv = last[v];
#pragma unroll
        for (int j = 0; j < LL; ++j) {
            if (j <= lastv) {
                int l = l15[j];
                if (l < 0) {
                    sHei[tid][j] = 0;
                    sRef[tid][j] = LEAF_BIT | id15[j];
                } else {
                    int r = r15[j];
                    int hl = sHei[tid][l], hr = sHei[tid][r];
                    int hh = 1 + (hl > hr ? hl : hr);
                    sHei[tid][j] = hh;
                    int pos = atomicAdd(&locCnt[hh], 1);
                    int flag = (j == lastv) ? ROOT_BIT : 0;
                    ebuf[tid][nInt] = make_int4(nInt | flag, id15[j], sRef[tid][l], sRef[tid][r]);
                    ebin[tid][nInt] = (hh << 16) | pos;
                    sRef[tid][j] = nInt;
                    ++nInt;
                }
            }
        }
    }
    // block-level inclusive scan of nInt -> compact slot bases
    scanBuf[tid] = nInt;
    __syncthreads();
    for (int d = 1; d < MT; d <<= 1) {
        int val = (tid >= d) ? scanBuf[tid - d] : 0;
        __syncthreads();
        scanBuf[tid] += val;
        __syncthreads();
    }
    if (tid == 0) blockBase = atomicAdd(&counts[31], scanBuf[MT - 1]);
    if (tid < 8) {
        int c = locCnt[tid];
        basePos[tid] = c ? atomicAdd(&counts[tid], c) : 0;
    }
    __syncthreads();
    int treeBase = blockBase + scanBuf[tid] - nInt;
    if (v < V && nInt > 0) rootSlot[v] = treeBase + nInt - 1;
    for (int e = 0; e < nInt; ++e) {
        int4 E  = ebuf[tid][e];
        int md  = ebin[tid][e];
        int hh  = md >> 16, pos = md & 0xFFFF;
        E.x += treeBase;                                   // ROOT_BIT preserved
        E.z = (E.z & LEAF_BIT) ? E.z : (E.z + treeBase);
        E.w = (E.w & LEAF_BIT) ? E.w : (E.w + treeBase);
        lists[d_listOff[hh] + basePos[hh] + pos] = E;
    }
}

// ---------------- MFMA round body (shared by per-height + fused tail) --------------
// block = 8 waves, 32 nodes/group (2 chunks of 16).
// wave w owns cols {128p + 16w + ln15, p=0..4} = the 5 gates of dim 16w+ln15
// -> full in-register LSTM epilogue. Barriers per group keep the 8 waves'
// partial-row writes temporally clustered (round-6 lesson: removing them
// caused 10x partial-line writeback amplification).
__device__ __forceinline__ void round_body(const int4* __restrict__ list, int cnt,
                                           const __half* __restrict__ embT,
                                           const __half* __restrict__ WT,
                                           const float* __restrict__ biasSum,
                                           const __half* __restrict__ leafHh,
                                           const float* __restrict__ leafC,
                                           float* __restrict__ hInt, float* __restrict__ cInt,
                                           __half* __restrict__ hH,
                                           __half (*Ah)[264], int4* meta) {
    int nGroups = (cnt + 31) >> 5;
    int t = threadIdx.x;
    int lane = t & 63, wave = t >> 6;        // 8 waves
    int ln15 = lane & 15, quad = lane >> 4;
    int d = 16 * wave + ln15;
    float bs[5];
#pragma unroll
    for (int p = 0; p < 5; ++p) bs[p] = biasSum[p * 128 + d];
    const __half* wbase = WT + d * 256 + quad * 8;

    for (int grp = blockIdx.x; grp < nGroups; grp += gridDim.x) {
        int base = grp * 32;
        int rows = cnt - base; if (rows > 32) rows = 32;
        if (t < 32) {
            int4 E;
            if (t < rows) E = list[base + t];
            else { E.x = DUMMY_SLOT; E.y = 0; E.z = LEAF_BIT; E.w = LEAF_BIT; }
            meta[t] = E;
        }
        __syncthreads();
        // stage A rows: [hl fp16 (k 0..127) | hr fp16 (k 128..255)], 2 loads/thread
#pragma unroll
        for (int it = 0; it < 2; ++it) {
            int idx = t + it * 512;
            int m = idx >> 5, q = idx & 31;
            int ref = (q < 16) ? meta[m].z : meta[m].w;
            const __half* hs = (ref & LEAF_BIT) ? leafHh : hH;
            uint4 v = *(const uint4*)(hs + (ref & REF_MASK) * 128 + (q & 15) * 8);
            *(uint4*)(&Ah[m][q * 8]) = v;
        }
        // C init from fp16 padded table: one 16B load per (c,r); bias in f32 regs
        f32x4 acc[2][5];
#pragma unroll
        for (int c = 0; c < 2; ++c)
#pragma unroll
            for (int r = 0; r < 4; ++r) {
                int id = meta[c * 16 + quad * 4 + r].y;
                f16x8 ev = *(const f16x8*)((const void*)(embT + ((size_t)id * 128 + d) * 8));
#pragma unroll
                for (int p = 0; p < 5; ++p)
                    acc[c][p][r] = (float)ev[p] + bs[p];
            }
        __syncthreads();
        // K loop: 8 steps of 32; 5 B-frags + 2 A-frags -> 10 independent MFMAs
#pragma unroll 2
        for (int kb = 0; kb < 8; ++kb) {
            f16x8 bf[5];
#pragma unroll
            for (int p = 0; p < 5; ++p)
                bf[p] = *(const f16x8*)((const void*)(wbase + p * 32768 + kb * 32));
            f16x8 af[2];
#pragma unroll
            for (int c = 0; c < 2; ++c)
                af[c] = *(const f16x8*)((const void*)&Ah[c * 16 + ln15][kb * 32 + quad * 8]);
#pragma unroll
            for (int p = 0; p < 5; ++p)
#pragma unroll
                for (int c = 0; c < 2; ++c)
                    acc[c][p] = __builtin_amdgcn_mfma_f32_16x16x32_f16(af[c], bf[p], acc[c][p], 0, 0, 0);
        }
        // in-register LSTM epilogue: dim d, gates = p
#pragma unroll
        for (int c = 0; c < 2; ++c)
#pragma unroll
            for (int r = 0; r < 4; ++r) {
                int4 E = meta[c * 16 + quad * 4 + r];
                float ig = acc[c][0][r], lfg = acc[c][1][r], rfg = acc[c][2][r];
                float og = acc[c][3][r], ug = acc[c][4][r];
                float cl = ((E.z & LEAF_BIT) ? leafC : cInt)[(E.z & REF_MASK) * 128 + d];
                float cr = ((E.w & LEAF_BIT) ? leafC : cInt)[(E.w & REF_MASK) * 128 + d];
                float cc = sigm(ig) * tanhf(ug) + sigm(lfg) * cl + sigm(rfg) * cr;
                float hh2 = sigm(og) * tanhf(cc);
                int slot = E.x & SLOT_MASK;
                if (E.x & ROOT_BIT) {
                    hInt[slot * 128 + d] = hh2;      // root: only f32 h is read (gather)
                } else {
                    cInt[slot * 128 + d] = cc;       // non-root: c + fp16 h are read
                    hH[slot * 128 + d] = __float2half(hh2);
                }
            }
        __syncthreads();   // protect meta/Ah before next group
    }
}

__launch_bounds__(512, 4)
__global__ void round_mfma(const int4* __restrict__ list, const int* __restrict__ cntPtr,
                           const __half* __restrict__ embT, const __half* __restrict__ WT,
                           const float* __restrict__ biasSum,
                           const __half* __restrict__ leafHh, const float* __restrict__ leafC,
                           float* __restrict__ hInt, float* __restrict__ cInt,
                           __half* __restrict__ hH) {
    __shared__ __half Ah[32][264];
    __shared__ int4 meta[32];
    round_body(list, *cntPtr, embT, WT, biasSum, leafHh, leafC, hInt, cInt, hH, Ah, meta);
}

// Counting grid barrier among n co-resident blocks. RELAXED poll (no per-poll
// cache inv); release/acquire paid once via __threadfence (round-3 lesson).
__device__ __forceinline__ void grid_barrier_n(int* bar, int n) {
    __syncthreads();
    if (threadIdx.x == 0) {
        __threadfence();
        __hip_atomic_fetch_add(bar, 1, __ATOMIC_RELAXED, __HIP_MEMORY_SCOPE_AGENT);
        while (__hip_atomic_load(bar, __ATOMIC_RELAXED, __HIP_MEMORY_SCOPE_AGENT) < n)
            __builtin_amdgcn_s_sleep(8);
        __threadfence();
    }
    __syncthreads();
}

// ---------------- fused tail: heights 5..7 in one 8-block dispatch ----------------
#define NTAIL 8
__launch_bounds__(512, 4)
__global__ void tail_mfma(const int4* __restrict__ lists, const int* __restrict__ counts,
                          const __half* __restrict__ embT, const __half* __restrict__ WT,
                          const float* __restrict__ biasSum,
                          const __half* __restrict__ leafHh, const float* __restrict__ leafC,
                          float* __restrict__ hInt, float* __restrict__ cInt,
                          __half* __restrict__ hH, int* __restrict__ bar) {
    __shared__ __half Ah[32][264];
    __shared__ int4 meta[32];
#pragma unroll 1
    for (int h = 5; h <= 7; ++h) {
        round_body(lists + d_listOff[h], counts[h], embT, WT, biasSum,
                   leafHh, leafC, hInt, cInt, hH, Ah, meta);
        if (h < 7) grid_barrier_n(&bar[h - 5], NTAIL);
    }
}

// ---------------- final gather: out[b,s,:] = h_root[input[b,s]] ----------------
__global__ void gather_kernel(const int* __restrict__ input,
                              const int* __restrict__ rootSlot,
                              const float* __restrict__ hInt,
                              float4* __restrict__ out) {
    int idx = blockIdx.x * 256 + threadIdx.x;   // < OUTN/4
    int token = input[idx >> 5];
    int d = idx & 31;
    out[idx] = ((const float4*)hInt)[rootSlot[token] * 32 + d];
}

extern "C" void kernel_launch(void* const* d_in, const int* in_sizes, int n_in,
                              void* d_out, int out_size, void* d_ws, size_t ws_size,
                              hipStream_t stream) {
    const int*   input    = (const int*)d_in[0];
    const int*   node_ids = (const int*)d_in[1];
    const int*   left     = (const int*)d_in[2];
    const int*   right    = (const int*)d_in[3];
    const int*   last     = (const int*)d_in[4];
    const float* emb      = (const float*)d_in[5];
    const float* Wl       = (const float*)d_in[6];
    const float* Wlb      = (const float*)d_in[7];
    const float* Wr       = (const float*)d_in[8];
    const float* Wrb      = (const float*)d_in[9];
    float* out = (float*)d_out;

    char* ws = (char*)d_ws;
    int*    counts   = (int*)(ws + OFF_COUNTS);
    int*    rootSlot = (int*)(ws + OFF_ROOT);
    int4*   lists    = (int4*)(ws + OFF_LISTS);
    float*  leafC    = (float*)(ws + OFF_LEAFC);
    __half* leafHh   = (__half*)(ws + OFF_LEAFHH);
    __half* embT     = (__half*)(ws + OFF_EMBT);
    __half* WT       = (__half*)(ws + OFF_WT);
    float*  biasSum  = (float*)(ws + OFF_BIAS);
    float*  hInt     = (float*)(ws + OFF_HINT);
    float*  cInt     = (float*)(ws + OFF_CINT);
    __half* hH       = (__half*)(ws + OFF_HH);
    unsigned char* usedp = (unsigned char*)(ws + OFF_USED);

    (void)hipMemsetAsync(counts, 0, 128, stream);   // counts + tail barrier slots
    (void)hipMemsetAsync(usedp, 0, V, stream);

    prep_kernel<<<1024, 256, 0, stream>>>(input, emb, Wl, Wlb, Wr, Wrb,
                                          leafC, leafHh, embT, WT, biasSum, usedp);
    meta_kernel<<<(V + MT - 1) / MT, MT, 0, stream>>>(node_ids, left, right, last, usedp,
                                                      counts, rootSlot, lists);

    static const int h_listOff[8] = {0, 0, 80000, 120000, 160000, 180000, 200000, 220000};
    static const int h_grid[8]    = {0, 1024, 512, 256, 128, 0, 0, 0};
    for (int h = 1; h <= 4; ++h) {
        round_mfma<<<h_grid[h], 512, 0, stream>>>(
            lists + h_listOff[h], counts + h,
            embT, WT, biasSum, leafHh, leafC, hInt, cInt, hH);
    }
    tail_mfma<<<NTAIL, 512, 0, stream>>>(lists, counts, embT, WT, biasSum,
                                         leafHh, leafC, hInt, cInt, hH, counts + 16);

    gather_kernel<<<OUTN / 4 / 256, 256, 0, stream>>>(input, rootSlot, hInt, (float4*)out);
}

// Round 8
// 326.275 us; speedup vs baseline: 1.6004x; 1.4333x over previous
//
#include <hip/hip_runtime.h>
#include <hip/hip_fp16.h>
#include <math.h>

// Problem constants
#define V    20000
#define SCV  4000
#define LL   15
#define OUTN (16384 * 128)   // B*S*D

#define LEAF_BIT 0x40000000
#define REF_MASK 0x3FFFFFFF
#define ROOT_BIT 0x20000000   // on E.x only: node is a tree root (write hInt only)
#define SLOT_MASK 0x1FFFFFFF
#define DUMMY_SLOT 89999     // total internal nodes ~80k < 89999

// ---- workspace layout (bytes) ----
#define OFF_COUNTS 0
#define OFF_ROOT   128
#define OFF_LISTS  80384
#define OFF_LEAFC  5968384
#define OFF_LEAFHH 8016384
#define OFF_EMBT   9040384     // fp16 [4000][128][8] = 8.192 MB
#define OFF_WT     19280384
#define OFF_BIAS   19608064
#define OFF_HINT   19610624
#define OFF_CINT   65690624
#define OFF_HH     111770624
#define OFF_USED   134810624

// per-height lists: h1@0 (cap 80000), h2@80000, h3@120000, h4@160000,
// h5@180000, h6@200000, h7@220000
__device__ __constant__ int d_listOff[8] = {0, 0, 80000, 120000, 160000, 180000, 200000, 220000};

#define MT 128

typedef _Float16 f16x8 __attribute__((ext_vector_type(8)));
typedef float    f32x4 __attribute__((ext_vector_type(4)));

__device__ __forceinline__ float sigm(float x) { return 1.0f / (1.0f + expf(-x)); }

// ---------------- prep: leaf states + embT + WT transpose + biasSum + mark ----------
// grid 1024 x 256. Blocks 0..39 also do one 64x64 WT tile; block 41 does biasSum.
__global__ void prep_kernel(const int* __restrict__ input,
                            const float* __restrict__ emb,
                            const float* __restrict__ Wl, const float* __restrict__ Wlb,
                            const float* __restrict__ Wr, const float* __restrict__ Wrb,
                            float* __restrict__ leafC, __half* __restrict__ leafHh,
                            __half* __restrict__ embT,
                            __half* __restrict__ WT, float* __restrict__ biasSum,
                            unsigned char* __restrict__ used) {
    __shared__ float T[64][65];
    int t = threadIdx.x, bid = blockIdx.x;
    // leaf (h,c) per sub-char id: 2 rows per block-iter
    for (int r = bid * 2 + (t >> 7); r < SCV; r += gridDim.x * 2) {
        int i = t & 127;
        const float* e = emb + r * 640;
        float c = sigm(e[i]) * tanhf(e[512 + i]);
        float h = sigm(e[384 + i]) * tanhf(c);
        leafC[r * 128 + i] = c;
        leafHh[r * 128 + i] = __float2half(h);
    }
    // embT[id][d][0..4] = fp16(emb[id][p*128+d]), [5..7]=0  (one 16B row per (id,d))
    for (int idx = bid * 256 + t; idx < SCV * 128; idx += gridDim.x * 256) {
        int id = idx >> 7, dd = idx & 127;
        const float* e = emb + id * 640 + dd;
        __half v[8];
#pragma unroll
        for (int p = 0; p < 5; ++p) v[p] = __float2half(e[p * 128]);
        v[5] = __float2half(0.f); v[6] = v[5]; v[7] = v[5];
        *(uint4*)(embT + (size_t)idx * 8) = *(const uint4*)v;
    }
    // mark used tokens
    for (int i = bid * 256 + t; i < 16384; i += gridDim.x * 256)
        used[input[i]] = 1;
    // bias sum
    if (bid == 41)
        for (int i = t; i < 640; i += 256) biasSum[i] = Wlb[i] + Wrb[i];
    // WT[n][k] = fp16([Wl;Wr][k][n]); 40 tiles of 64x64, one per block 0..39
    if (bid < 40) {
        int kb = (bid & 3) * 64, nb = (bid >> 2) * 64;
        int tx = t & 63, ty = t >> 6;            // 256 threads: ty 0..3
        for (int kk = ty; kk < 64; kk += 4) {
            int k = kb + kk;
            const float* Wsrc = (k < 128) ? (Wl + k * 640) : (Wr + (k - 128) * 640);
            T[kk][tx] = Wsrc[nb + tx];
        }
        __syncthreads();
        for (int nn = ty; nn < 64; nn += 4)
            WT[(nb + nn) * 256 + kb + tx] = __float2half(T[tx][nn]);
    }
}

// ---------------- metadata: heights, compact slots, per-height lists ----------------
__global__ void meta_kernel(const int* __restrict__ node_ids,
                            const int* __restrict__ left,
                            const int* __restrict__ right,
                            const int* __restrict__ last,
                            const unsigned char* __restrict__ used,
                            int* __restrict__ counts,
                            int* __restrict__ rootSlot,
                            int4* __restrict__ lists) {
    __shared__ int  sHei[MT][17];
    __shared__ int  sRef[MT][17];
    __shared__ int4 ebuf[MT][7];
    __shared__ int  ebin[MT][7];
    __shared__ int  locCnt[8];
    __shared__ int  basePos[8];
    __shared__ int  scanBuf[MT];
    __shared__ int  blockBase;

    int tid = threadIdx.x;
    if (tid < 8) locCnt[tid] = 0;
    __syncthreads();

    int v = blockIdx.x * MT + tid;
    int nInt = 0;
    if (v < V && used[v]) {
        int l15[LL], r15[LL], id15[LL];
#pragma unroll
        for (int j = 0; j < LL; ++j) {
            l15[j]  = left[v * LL + j];
            r15[j]  = right[v * LL + j];
            id15[j] = node_ids[v * LL + j];
        }
        int lastv = last[v];
#pragma unroll
        for (int j = 0; j < LL; ++j) {
            if (j <= lastv) {
                int l = l15[j];
                if (l < 0) {
                    sHei[tid][j] = 0;
                    sRef[tid][j] = LEAF_BIT | id15[j];
                } else {
                    int r = r15[j];
                    int hl = sHei[tid][l], hr = sHei[tid][r];
                    int hh = 1 + (hl > hr ? hl : hr);
                    sHei[tid][j] = hh;
                    int pos = atomicAdd(&locCnt[hh], 1);
                    int flag = (j == lastv) ? ROOT_BIT : 0;
                    ebuf[tid][nInt] = make_int4(nInt | flag, id15[j], sRef[tid][l], sRef[tid][r]);
                    ebin[tid][nInt] = (hh << 16) | pos;
                    sRef[tid][j] = nInt;
                    ++nInt;
                }
            }
        }
    }
    // block-level inclusive scan of nInt -> compact slot bases
    scanBuf[tid] = nInt;
    __syncthreads();
    for (int d = 1; d < MT; d <<= 1) {
        int val = (tid >= d) ? scanBuf[tid - d] : 0;
        __syncthreads();
        scanBuf[tid] += val;
        __syncthreads();
    }
    if (tid == 0) blockBase = atomicAdd(&counts[31], scanBuf[MT - 1]);
    if (tid < 8) {
        int c = locCnt[tid];
        basePos[tid] = c ? atomicAdd(&counts[tid], c) : 0;
    }
    __syncthreads();
    int treeBase = blockBase + scanBuf[tid] - nInt;
    if (v < V && nInt > 0) rootSlot[v] = treeBase + nInt - 1;
    for (int e = 0; e < nInt; ++e) {
        int4 E  = ebuf[tid][e];
        int md  = ebin[tid][e];
        int hh  = md >> 16, pos = md & 0xFFFF;
        E.x += treeBase;                                   // ROOT_BIT preserved
        E.z = (E.z & LEAF_BIT) ? E.z : (E.z + treeBase);
        E.w = (E.w & LEAF_BIT) ? E.w : (E.w + treeBase);
        lists[d_listOff[hh] + basePos[hh] + pos] = E;
    }
}

// ---------------- MFMA round: all heights 1..7, unified K=256 ----------------
// block = 8 waves, 32 nodes/group (2 chunks of 16).
// wave w owns cols {128p + 16w + ln15, p=0..4} = the 5 gates of dim 16w+ln15
// -> full in-register LSTM epilogue. Per-group barriers keep the 8 waves'
// partial-row writes temporally clustered (round-6 lesson: removing them
// caused 10x partial-line writeback amplification).
__launch_bounds__(512, 4)
__global__ void round_mfma(const int4* __restrict__ list, const int* __restrict__ cntPtr,
                           const __half* __restrict__ embT, const __half* __restrict__ WT,
                           const float* __restrict__ biasSum,
                           const __half* __restrict__ leafHh, const float* __restrict__ leafC,
                           float* __restrict__ hInt, float* __restrict__ cInt,
                           __half* __restrict__ hH) {
    __shared__ __half Ah[32][264];   // +8 fp16 pad per row
    __shared__ int4 meta[32];
    int cnt = *cntPtr;
    int nGroups = (cnt + 31) >> 5;
    int t = threadIdx.x;
    int lane = t & 63, wave = t >> 6;        // 8 waves
    int ln15 = lane & 15, quad = lane >> 4;
    int d = 16 * wave + ln15;
    float bs[5];
#pragma unroll
    for (int p = 0; p < 5; ++p) bs[p] = biasSum[p * 128 + d];
    const __half* wbase = WT + d * 256 + quad * 8;

    for (int grp = blockIdx.x; grp < nGroups; grp += gridDim.x) {
        int base = grp * 32;
        int rows = cnt - base; if (rows > 32) rows = 32;
        if (t < 32) {
            int4 E;
            if (t < rows) E = list[base + t];
            else { E.x = DUMMY_SLOT; E.y = 0; E.z = LEAF_BIT; E.w = LEAF_BIT; }
            meta[t] = E;
        }
        __syncthreads();
        // stage A rows: [hl fp16 (k 0..127) | hr fp16 (k 128..255)], 2 loads/thread
#pragma unroll
        for (int it = 0; it < 2; ++it) {
            int idx = t + it * 512;
            int m = idx >> 5, q = idx & 31;
            int ref = (q < 16) ? meta[m].z : meta[m].w;
            const __half* hs = (ref & LEAF_BIT) ? leafHh : hH;
            uint4 v = *(const uint4*)(hs + (ref & REF_MASK) * 128 + (q & 15) * 8);
            *(uint4*)(&Ah[m][q * 8]) = v;
        }
        // C init from fp16 padded table: one 16B load per (c,r); bias in f32 regs
        f32x4 acc[2][5];
#pragma unroll
        for (int c = 0; c < 2; ++c)
#pragma unroll
            for (int r = 0; r < 4; ++r) {
                int id = meta[c * 16 + quad * 4 + r].y;
                f16x8 ev = *(const f16x8*)((const void*)(embT + ((size_t)id * 128 + d) * 8));
#pragma unroll
                for (int p = 0; p < 5; ++p)
                    acc[c][p][r] = (float)ev[p] + bs[p];
            }
        __syncthreads();
        // K loop: 8 steps of 32; 5 B-frags + 2 A-frags -> 10 independent MFMAs
#pragma unroll 2
        for (int kb = 0; kb < 8; ++kb) {
            f16x8 bf[5];
#pragma unroll
            for (int p = 0; p < 5; ++p)
                bf[p] = *(const f16x8*)((const void*)(wbase + p * 32768 + kb * 32));
            f16x8 af[2];
#pragma unroll
            for (int c = 0; c < 2; ++c)
                af[c] = *(const f16x8*)((const void*)&Ah[c * 16 + ln15][kb * 32 + quad * 8]);
#pragma unroll
            for (int p = 0; p < 5; ++p)
#pragma unroll
                for (int c = 0; c < 2; ++c)
                    acc[c][p] = __builtin_amdgcn_mfma_f32_16x16x32_f16(af[c], bf[p], acc[c][p], 0, 0, 0);
        }
        // in-register LSTM epilogue: dim d, gates = p
#pragma unroll
        for (int c = 0; c < 2; ++c)
#pragma unroll
            for (int r = 0; r < 4; ++r) {
                int4 E = meta[c * 16 + quad * 4 + r];
                float ig = acc[c][0][r], lfg = acc[c][1][r], rfg = acc[c][2][r];
                float og = acc[c][3][r], ug = acc[c][4][r];
                float cl = ((E.z & LEAF_BIT) ? leafC : cInt)[(E.z & REF_MASK) * 128 + d];
                float cr = ((E.w & LEAF_BIT) ? leafC : cInt)[(E.w & REF_MASK) * 128 + d];
                float cc = sigm(ig) * tanhf(ug) + sigm(lfg) * cl + sigm(rfg) * cr;
                float hh2 = sigm(og) * tanhf(cc);
                int slot = E.x & SLOT_MASK;
                if (E.x & ROOT_BIT) {
                    hInt[slot * 128 + d] = hh2;      // root: only f32 h is read (gather)
                } else {
                    cInt[slot * 128 + d] = cc;       // non-root: c + fp16 h are read
                    hH[slot * 128 + d] = __float2half(hh2);
                }
            }
        __syncthreads();   // protect meta/Ah before next group
    }
}

// ---------------- final gather: out[b,s,:] = h_root[input[b,s]] ----------------
__global__ void gather_kernel(const int* __restrict__ input,
                              const int* __restrict__ rootSlot,
                              const float* __restrict__ hInt,
                              float4* __restrict__ out) {
    int idx = blockIdx.x * 256 + threadIdx.x;   // < OUTN/4
    int token = input[idx >> 5];
    int d = idx & 31;
    out[idx] = ((const float4*)hInt)[rootSlot[token] * 32 + d];
}

extern "C" void kernel_launch(void* const* d_in, const int* in_sizes, int n_in,
                              void* d_out, int out_size, void* d_ws, size_t ws_size,
                              hipStream_t stream) {
    const int*   input    = (const int*)d_in[0];
    const int*   node_ids = (const int*)d_in[1];
    const int*   left     = (const int*)d_in[2];
    const int*   right    = (const int*)d_in[3];
    const int*   last     = (const int*)d_in[4];
    const float* emb      = (const float*)d_in[5];
    const float* Wl       = (const float*)d_in[6];
    const float* Wlb      = (const float*)d_in[7];
    const float* Wr       = (const float*)d_in[8];
    const float* Wrb      = (const float*)d_in[9];
    float* out = (float*)d_out;

    char* ws = (char*)d_ws;
    int*    counts   = (int*)(ws + OFF_COUNTS);
    int*    rootSlot = (int*)(ws + OFF_ROOT);
    int4*   lists    = (int4*)(ws + OFF_LISTS);
    float*  leafC    = (float*)(ws + OFF_LEAFC);
    __half* leafHh   = (__half*)(ws + OFF_LEAFHH);
    __half* embT     = (__half*)(ws + OFF_EMBT);
    __half* WT       = (__half*)(ws + OFF_WT);
    float*  biasSum  = (float*)(ws + OFF_BIAS);
    float*  hInt     = (float*)(ws + OFF_HINT);
    float*  cInt     = (float*)(ws + OFF_CINT);
    __half* hH       = (__half*)(ws + OFF_HH);
    unsigned char* usedp = (unsigned char*)(ws + OFF_USED);

    (void)hipMemsetAsync(counts, 0, 128, stream);
    (void)hipMemsetAsync(usedp, 0, V, stream);

    prep_kernel<<<1024, 256, 0, stream>>>(input, emb, Wl, Wlb, Wr, Wrb,
                                          leafC, leafHh, embT, WT, biasSum, usedp);
    meta_kernel<<<(V + MT - 1) / MT, MT, 0, stream>>>(node_ids, left, right, last, usedp,
                                                      counts, rootSlot, lists);

    static const int h_listOff[8] = {0, 0, 80000, 120000, 160000, 180000, 200000, 220000};
    static const int h_grid[8]    = {0, 1024, 512, 256, 128, 32, 16, 8};
    for (int h = 1; h <= 7; ++h) {
        round_mfma<<<h_grid[h], 512, 0, stream>>>(
            lists + h_listOff[h], counts + h,
            embT, WT, biasSum, leafHh, leafC, hInt, cInt, hH);
    }

    gather_kernel<<<OUTN / 4 / 256, 256, 0, stream>>>(input, rootSlot, hInt, (float4*)out);
}